// Round 13
// baseline (84.475 us; speedup 1.0000x reference)
//
#include <hip/hip_runtime.h>
#include <math.h>

#define VOCAB 21128
#define DD 768
#define SS 50
#define TT 5
#define BB 512
#define EE 128
#define CC 10
#define V20 (VOCAB * 20)
#define NG 2560   // utterance graphs; resp graphs are G in [NG, NG+512)
#define NALL 3072 // NG + BB

// ---------------- kernel 1: hvp[kh][21128][20] = emb[:, kh-half] @ W-half ----------------
// r13 CHANGE: W consumed via v_readlane from VGPR-resident slices (16 coalesced vector
// loads/lane, once) instead of per-wave s_load streams. r10's per-wave-disjoint W
// slices thrashed the 16KB scalar L1 (same mechanism as r11's regression). readlane
// (slot,lane) constants are compile-time; result lands in SGPR -> FMA scalar operand.
__global__ __launch_bounds__(512) void k_vocab(const float* __restrict__ emb,
                                               const float* __restrict__ Wconv,
                                               const float* __restrict__ Wcross,
                                               float* __restrict__ hvp) {
    __shared__ float tile[8][64][21];  // 43008 B (cols 16-20 = reduce scratch headroom)
    const int wv = threadIdx.x >> 6, lane = threadIdx.x & 63;
    const int rowbase = blockIdx.x * 64;
    const int rsub = lane >> 2, m = lane & 3;

    const int d0w = blockIdx.y * 384 + wv * 48;   // this wave's 48-d slice

    // ---- W slice (48 d x 10 c, conv + cross) -> 8+8 VGPRs via coalesced loads ----
    // flat index f = dd*10 + c  (dd in [0,48), c in [0,10)) -> held at lane f&63, slot f>>6
    float wcv[8], wxv[8];
#pragma unroll
    for (int j = 0; j < 8; ++j) {
        int fidx = j * 64 + lane;
        if (fidx > 479) fidx = 479;               // slots beyond the 480-slice: unused clamp
        wcv[j] = Wconv[d0w * 10 + fidx];
        wxv[j] = Wcross[d0w * 10 + fidx];
    }

    // ---- prefetch all 12 emb float4 (r10 pattern) ----
    float4 v[12];
#pragma unroll
    for (int ch = 0; ch < 3; ++ch) {
#pragma unroll
        for (int it = 0; it < 4; ++it) {
            int row = it * 16 + rsub;
            long r = rowbase + row;
            if (r >= VOCAB) r = VOCAB - 1;
            v[ch * 4 + it] = *(const float4*)(emb + r * DD + d0w + ch * 16 + m * 4);
        }
    }

    float acc[20];
#pragma unroll
    for (int c = 0; c < 20; c++) acc[c] = 0.f;

#pragma unroll
    for (int ch = 0; ch < 3; ++ch) {
#pragma unroll
        for (int it = 0; it < 4; ++it) {
            const int row = it * 16 + rsub;
            const float4 w = v[ch * 4 + it];
            tile[wv][row][m * 4 + 0] = w.x;
            tile[wv][row][m * 4 + 1] = w.y;
            tile[wv][row][m * 4 + 2] = w.z;
            tile[wv][row][m * 4 + 3] = w.w;
        }
        // same-wave ds_write -> ds_read: in-order DS pipe
#pragma unroll
        for (int dd = 0; dd < 16; ++dd) {
            const float e = tile[wv][lane][dd];
            const int fbase = (ch * 16 + dd) * 10;    // compile-time
#pragma unroll
            for (int c = 0; c < 10; c++) {
                const int f = fbase + c;              // compile-time -> const slot & lane
                const float wc = __uint_as_float(
                    __builtin_amdgcn_readlane(__float_as_uint(wcv[f >> 6]), f & 63));
                const float wx = __uint_as_float(
                    __builtin_amdgcn_readlane(__float_as_uint(wxv[f >> 6]), f & 63));
                acc[c] = fmaf(e, wc, acc[c]);
                acc[10 + c] = fmaf(e, wx, acc[10 + c]);
            }
        }
    }

    __syncthreads();
    float* pp = &tile[0][0][0];  // reuse as part[8][64][20] (10240 <= 10752 floats)
#pragma unroll
    for (int c = 0; c < 20; c++) pp[wv * 1280 + lane * 20 + c] = acc[c];
    __syncthreads();
    float* outp = hvp + (long)blockIdx.y * V20;
    for (int i = threadIdx.x; i < 1280; i += 512) {
        int row = i / 20;
        long r = rowbase + row;
        if (r < VOCAB) {
            float s = 0.f;
#pragma unroll
            for (int w = 0; w < 8; ++w) s += pp[w * 1280 + i];
            outp[r * 20 + (i - row * 20)] = s;
        }
    }
}

// ---------------- kernel 2: unified GCN for all 3072 graphs -> P[G][50][20] ----------------
// (r12 version, unchanged)
__global__ __launch_bounds__(256) void k_gcn(const int* __restrict__ ctok,
                                             const int* __restrict__ cadj,
                                             const int* __restrict__ rtok,
                                             const int* __restrict__ radj,
                                             const float* __restrict__ hvp,
                                             const float* __restrict__ convb,
                                             const float* __restrict__ att,
                                             float* __restrict__ P) {
    __shared__ float attT[SS][51];
    __shared__ float hcv[4][SS][12];
    __shared__ float hcx[4][SS][12];
    __shared__ float aggL[4][SS][11];
    __shared__ int dgS[4][64];
    const int tid = threadIdx.x, wv = tid >> 6, lane = tid & 63;
    const int G = blockIdx.x * 4 + wv;

    for (int i = tid; i < SS * SS; i += 256) { int p = i / SS, s = i - p * SS; attT[s][p] = att[i]; }
    __syncthreads();   // only barrier

    const int* tb;
    const int* ab;
    if (G < NG) { tb = ctok + (long)G * SS; ab = cadj + (long)G * 2 * EE; }
    else        { int b = G - NG; tb = rtok + (long)b * SS; ab = radj + (long)b * 2 * EE; }

    const int e1s = ab[lane], e2s = ab[lane + 64];
    const int e1d = ab[EE + lane], e2d = ab[EE + lane + 64];
    const int myTok = (lane < SS) ? tb[lane] : 0;

    dgS[wv][lane] = 0;
    atomicAdd(&dgS[wv][e1d], 1);
    atomicAdd(&dgS[wv][e2d], 1);

    const float4* hv4 = (const float4*)hvp;
#pragma unroll
    for (int it = 0; it < 4; ++it) {
        const int idx = it * 64 + lane;
        int row = idx / 5;
        const int q = idx - row * 5;
        const int rowc = (row < SS) ? row : (SS - 1);
        const int t = __shfl(myTok, rowc);            // all 64 lanes execute
        if (idx < SS * 5) {
            const float4 a = hv4[(long)t * 5 + q];
            const float4 b = hv4[(long)(VOCAB * 5) + (long)t * 5 + q];
            const float4 w = make_float4(a.x + b.x, a.y + b.y, a.z + b.z, a.w + b.w);
            if (q == 0)      *(float4*)&hcv[wv][row][0] = w;
            else if (q == 1) *(float4*)&hcv[wv][row][4] = w;
            else if (q == 2) { hcv[wv][row][8] = w.x; hcv[wv][row][9] = w.y;
                               hcx[wv][row][0] = w.z; hcx[wv][row][1] = w.w; }
            else if (q == 3) { *(float2*)&hcx[wv][row][2] = make_float2(w.x, w.y);
                               *(float2*)&hcx[wv][row][4] = make_float2(w.z, w.w); }
            else             { *(float2*)&hcx[wv][row][6] = make_float2(w.x, w.y);
                               *(float2*)&hcx[wv][row][8] = make_float2(w.z, w.w); }
        }
    }

    float dv = 0.f;
    if (lane < SS) dv = rsqrtf((float)(dgS[wv][lane] + 1));

    float* aggW = &aggL[wv][0][0];
    for (int i = lane; i < SS * 11; i += 64) aggW[i] = 0.f;
    const float n1 = __shfl(dv, e1s) * __shfl(dv, e1d);
    const float n2 = __shfl(dv, e2s) * __shfl(dv, e2d);
#pragma unroll
    for (int c = 0; c < CC; c++) atomicAdd(&aggW[e1d * 11 + c], hcv[wv][e1s][c] * n1);
#pragma unroll
    for (int c = 0; c < CC; c++) atomicAdd(&aggW[e2d * 11 + c], hcv[wv][e2s][c] * n2);

    const int pc = (lane < SS) ? lane : (SS - 1);
    float xo[CC];
#pragma unroll
    for (int c = 0; c < CC; c++) xo[c] = hcx[wv][pc][c];

    const int p = lane;
    if (p < SS) {
        float gcn[CC];
        const float dp2 = dv * dv;
        const float4 s0 = *(const float4*)&hcv[wv][p][0];
        const float4 s1 = *(const float4*)&hcv[wv][p][4];
        const float s8 = hcv[wv][p][8], s9 = hcv[wv][p][9];
        gcn[0] = aggW[p * 11 + 0] + s0.x * dp2 + convb[0];
        gcn[1] = aggW[p * 11 + 1] + s0.y * dp2 + convb[1];
        gcn[2] = aggW[p * 11 + 2] + s0.z * dp2 + convb[2];
        gcn[3] = aggW[p * 11 + 3] + s0.w * dp2 + convb[3];
        gcn[4] = aggW[p * 11 + 4] + s1.x * dp2 + convb[4];
        gcn[5] = aggW[p * 11 + 5] + s1.y * dp2 + convb[5];
        gcn[6] = aggW[p * 11 + 6] + s1.z * dp2 + convb[6];
        gcn[7] = aggW[p * 11 + 7] + s1.w * dp2 + convb[7];
        gcn[8] = aggW[p * 11 + 8] + s8 * dp2 + convb[8];
        gcn[9] = aggW[p * 11 + 9] + s9 * dp2 + convb[9];

        float ax[CC];
#pragma unroll
        for (int c = 0; c < CC; c++) ax[c] = 0.f;
#pragma unroll 5
        for (int s = 0; s < SS; ++s) {
            const float a = attT[s][p];
#pragma unroll
            for (int c = 0; c < CC; c++) {
                const float xs = __uint_as_float(
                    __builtin_amdgcn_readlane(__float_as_uint(xo[c]), s));
                ax[c] = fmaf(a, xs, ax[c]);
            }
        }
        float4* o4 = (float4*)(P + (long)G * 1000 + p * 20);
        o4[0] = make_float4(gcn[0], gcn[1], gcn[2], gcn[3]);
        o4[1] = make_float4(gcn[4], gcn[5], gcn[6], gcn[7]);
        o4[2] = make_float4(gcn[8], gcn[9], ax[0], ax[1]);
        o4[3] = make_float4(ax[2], ax[3], ax[4], ax[5]);
        o4[4] = make_float4(ax[6], ax[7], ax[8], ax[9]);
    }
}

// ---------------- kernel 3: mpm, one wave per (g, which) = 5120 waves ----------------
// (r12 version, unchanged)
__global__ __launch_bounds__(256) void k_mpm(const float* __restrict__ P,
                                             const float* __restrict__ assign,
                                             const float* __restrict__ W1, const float* __restrict__ b1,
                                             const float* __restrict__ W2, const float* __restrict__ b2,
                                             float* __restrict__ guG,
                                             float* __restrict__ grG) {
    __shared__ float W2T[20][21];
    __shared__ float asgL[SS][11];
    __shared__ float h1L[4][SS][20];
    const int tid = threadIdx.x, wv = tid >> 6, lane = tid & 63;
    const int wid = blockIdx.x * 4 + wv;
    const int g = wid >> 1, which = wid & 1;
    const int b = g / TT;

    for (int i = tid; i < 400; i += 256) W2T[i % 20][i / 20] = W2[i];
    for (int i = tid; i < SS * CC; i += 256) asgL[i / CC][i % CC] = assign[i];
    __syncthreads();   // only barrier

    const float* Pc = P + (long)g * 1000;
    const float* Pr = P + (long)(NG + b) * 1000;
    const float* selfP = which ? Pr : Pc;
    const float* croP  = which ? Pc : Pr;

    const int p = lane;
    float self[CC], cro[CC];
    if (p < SS) {
        const float4* s4 = (const float4*)(selfP + p * 20);
        const float4 a0 = s4[0], a1 = s4[1], a2 = s4[2];
        self[0] = a0.x; self[1] = a0.y; self[2] = a0.z; self[3] = a0.w;
        self[4] = a1.x; self[5] = a1.y; self[6] = a1.z; self[7] = a1.w;
        self[8] = a2.x; self[9] = a2.y;
        const float4* c4 = (const float4*)(croP + p * 20);
        const float4 b0 = c4[2], b1q = c4[3], b2q = c4[4];
        cro[0] = b0.z; cro[1] = b0.w;
        cro[2] = b1q.x; cro[3] = b1q.y; cro[4] = b1q.z; cro[5] = b1q.w;
        cro[6] = b2q.x; cro[7] = b2q.y; cro[8] = b2q.z; cro[9] = b2q.w;
    }

    const int j = lane % 20;
    const int grp = lane / 20;
    float w2r[20];
#pragma unroll
    for (int k = 0; k < 20; k++) w2r[k] = W2T[j][k];

    if (p < SS) {
        float num = 0.f, na = 0.f, nc2 = 0.f;
#pragma unroll
        for (int c = 0; c < CC; c++) {
            float av = asgL[p][c];
            float a = av * self[c];
            float cx = av * cro[c];
            num = fmaf(a, cx, num);
            na = fmaf(a, a, na);
            nc2 = fmaf(cx, cx, nc2);
        }
        float cosv = num / fmaxf(sqrtf(na) * sqrtf(nc2), 1e-8f);
        float h1[20];
#pragma unroll
        for (int q = 0; q < 20; q++) h1[q] = fmaf(cosv, W1[q], b1[q]);
#pragma unroll
        for (int k = 0; k < CC; k++) {
            float sv = self[k];
#pragma unroll
            for (int q = 0; q < 20; q++) h1[q] = fmaf(sv, W1[(k + 1) * 20 + q], h1[q]);
        }
        float4* hw = (float4*)&h1L[wv][p][0];
        hw[0] = make_float4(fmaxf(h1[0], 0.f), fmaxf(h1[1], 0.f), fmaxf(h1[2], 0.f), fmaxf(h1[3], 0.f));
        hw[1] = make_float4(fmaxf(h1[4], 0.f), fmaxf(h1[5], 0.f), fmaxf(h1[6], 0.f), fmaxf(h1[7], 0.f));
        hw[2] = make_float4(fmaxf(h1[8], 0.f), fmaxf(h1[9], 0.f), fmaxf(h1[10], 0.f), fmaxf(h1[11], 0.f));
        hw[3] = make_float4(fmaxf(h1[12], 0.f), fmaxf(h1[13], 0.f), fmaxf(h1[14], 0.f), fmaxf(h1[15], 0.f));
        hw[4] = make_float4(fmaxf(h1[16], 0.f), fmaxf(h1[17], 0.f), fmaxf(h1[18], 0.f), fmaxf(h1[19], 0.f));
    }

    float part = -1e30f;
    if (grp < 3) {
        const int s0 = grp * 17;
        const int s1 = (grp == 2) ? SS : (s0 + 17);
        for (int s = s0; s < s1; ++s) {
            const float* hr = &h1L[wv][s][0];
            float t = 0.f;
#pragma unroll
            for (int k = 0; k < 20; k++) t = fmaf(hr[k], w2r[k], t);
            part = fmaxf(part, t);
        }
    }
    const float a0 = __shfl(part, j);
    const float a1 = __shfl(part, j + 20);
    const float a2 = __shfl(part, j + 40);
    if (lane < 20) {
        float h2 = fmaxf(fmaxf(a0, a1), a2) + b2[lane];
        (which ? grG : guG)[(long)g * 20 + lane] = h2;
    }
}

// ---------------- kernel 4: final FFN + sum over T + sigmoid ----------------
__global__ __launch_bounds__(64) void k_final(const float* __restrict__ g_u, const float* __restrict__ g_r,
                                              const float* __restrict__ W1, const float* __restrict__ b1,
                                              const float* __restrict__ W2, const float* __restrict__ b2,
                                              float* __restrict__ out) {
    const int b = blockIdx.x, lane = threadIdx.x;
    float ssum = 0.f;
    for (int t = 0; t < TT; t++) {
        const float* gu = g_u + ((long)b * TT + t) * 20;
        const float* gr = g_r + ((long)b * TT + t) * 20;
        float feat[80];
#pragma unroll
        for (int k = 0; k < 20; k++) {
            float u = gu[k], r = gr[k];
            feat[k] = u;
            feat[20 + k] = r;
            feat[40 + k] = u * r;
            feat[60 + k] = fabsf(u - r);
        }
        if (lane < 40) {
            float hv = b1[lane];
#pragma unroll
            for (int k = 0; k < 80; k++) hv = fmaf(feat[k], W1[k * 40 + lane], hv);
            ssum += fmaxf(hv, 0.f) * W2[lane];
        }
    }
    for (int off = 32; off; off >>= 1) ssum += __shfl_xor(ssum, off);
    if (lane == 0) out[b] = 1.f / (1.f + expf(-(ssum + (float)TT * b2[0])));
}

extern "C" void kernel_launch(void* const* d_in, const int* in_sizes, int n_in,
                              void* d_out, int out_size, void* d_ws, size_t ws_size,
                              hipStream_t stream) {
    (void)in_sizes; (void)n_in; (void)out_size; (void)ws_size;
    const int* ctx_tok = (const int*)d_in[0];
    const int* resp_tok = (const int*)d_in[1];
    const int* ctx_adj = (const int*)d_in[2];
    const int* resp_adj = (const int*)d_in[3];
    const float* emb = (const float*)d_in[4];
    const float* convW = (const float*)d_in[5];
    const float* convb = (const float*)d_in[6];
    const float* crossW = (const float*)d_in[7];
    const float* att = (const float*)d_in[8];
    const float* assign = (const float*)d_in[9];
    const float* mpW1 = (const float*)d_in[10];
    const float* mpb1 = (const float*)d_in[11];
    const float* mpW2 = (const float*)d_in[12];
    const float* mpb2 = (const float*)d_in[13];
    const float* fW1 = (const float*)d_in[14];
    const float* fb1 = (const float*)d_in[15];
    const float* fW2 = (const float*)d_in[16];
    const float* fb2 = (const float*)d_in[17];

    float* ws = (float*)d_ws;
    float* hvp = ws;                       // [2][VOCAB][20]   = 845,120 floats
    float* P = hvp + 2 * V20;              // [3072][50][20]   = 3,072,000
    float* guG = P + (long)NALL * 1000;    // 51,200
    float* grG = guG + (long)NG * 20;      // 51,200
    float* outf = (float*)d_out;

    hipLaunchKernelGGL(k_vocab, dim3((VOCAB + 63) / 64, 2), dim3(512), 0, stream,
                       emb, convW, crossW, hvp);
    hipLaunchKernelGGL(k_gcn, dim3(NALL / 4), dim3(256), 0, stream,
                       ctx_tok, ctx_adj, resp_tok, resp_adj, hvp, convb, att, P);
    hipLaunchKernelGGL(k_mpm, dim3(NG * 2 / 4), dim3(256), 0, stream,
                       P, assign, mpW1, mpb1, mpW2, mpb2, guG, grG);
    hipLaunchKernelGGL(k_final, dim3(BB), dim3(64), 0, stream,
                       guG, grG, fW1, fb1, fW2, fb2, outf);
}

// Round 15
// 76.377 us; speedup vs baseline: 1.1060x; 1.1060x over previous
//
#include <hip/hip_runtime.h>
#include <math.h>

#define VOCAB 21128
#define DD 768
#define SS 50
#define TT 5
#define BB 512
#define EE 128
#define CC 10
#define V20 (VOCAB * 20)
#define NG 2560   // utterance graphs; resp graphs are G in [NG, NG+512)
#define NALL 3072 // NG + BB

// ---------------- kernel 0: attG[s][p] = att[p][s], rows padded to 52 ----------------
__global__ void k_prep(const float* __restrict__ att, float* __restrict__ attG) {
    int i = blockIdx.x * 64 + threadIdx.x;
    if (i < SS * SS) {
        int p = i / SS, s = i - p * SS;
        attG[s * 52 + p] = att[i];
    }
}

// ---------------- kernel 1: hvp[kh][21128][20] = emb[:, kh-half] @ W-half ----------------
// (r12 version, unchanged: prefetch 12 float4 + W via wave-uniform s_loads)
__global__ __launch_bounds__(512) void k_vocab(const float* __restrict__ emb,
                                               const float* __restrict__ Wconv,
                                               const float* __restrict__ Wcross,
                                               float* __restrict__ hvp) {
    __shared__ float tile[8][64][21];
    const int wv = threadIdx.x >> 6, lane = threadIdx.x & 63;
    const int rowbase = blockIdx.x * 64;
    const int rsub = lane >> 2, m = lane & 3;

    const int d0w = blockIdx.y * 384 + __builtin_amdgcn_readfirstlane(wv * 48);

    float4 v[12];
#pragma unroll
    for (int ch = 0; ch < 3; ++ch) {
#pragma unroll
        for (int it = 0; it < 4; ++it) {
            int row = it * 16 + rsub;
            long r = rowbase + row;
            if (r >= VOCAB) r = VOCAB - 1;
            v[ch * 4 + it] = *(const float4*)(emb + r * DD + d0w + ch * 16 + m * 4);
        }
    }

    float acc[20];
#pragma unroll
    for (int c = 0; c < 20; c++) acc[c] = 0.f;

#pragma unroll
    for (int ch = 0; ch < 3; ++ch) {
        const int d0 = d0w + ch * 16;
#pragma unroll
        for (int it = 0; it < 4; ++it) {
            const int row = it * 16 + rsub;
            const float4 w = v[ch * 4 + it];
            tile[wv][row][m * 4 + 0] = w.x;
            tile[wv][row][m * 4 + 1] = w.y;
            tile[wv][row][m * 4 + 2] = w.z;
            tile[wv][row][m * 4 + 3] = w.w;
        }
#pragma unroll
        for (int d = 0; d < 16; ++d) {
            float e = tile[wv][lane][d];
            const float* wc = Wconv + (d0 + d) * 10;
            const float* wx = Wcross + (d0 + d) * 10;
#pragma unroll
            for (int c = 0; c < 10; c++) {
                acc[c] = fmaf(e, wc[c], acc[c]);
                acc[10 + c] = fmaf(e, wx[c], acc[10 + c]);
            }
        }
    }

    __syncthreads();
    float* pp = &tile[0][0][0];
#pragma unroll
    for (int c = 0; c < 20; c++) pp[wv * 1280 + lane * 20 + c] = acc[c];
    __syncthreads();
    float* outp = hvp + (long)blockIdx.y * V20;
    for (int i = threadIdx.x; i < 1280; i += 512) {
        int row = i / 20;
        long r = rowbase + row;
        if (r < VOCAB) {
            float s = 0.f;
#pragma unroll
            for (int w = 0; w < 8; ++w) s += pp[w * 1280 + i];
            outp[r * 20 + (i - row * 20)] = s;
        }
    }
}

// ---------------- kernel 2: unified GCN for all 3072 graphs -> P[G][50][20] ----------------
// r12 dataflow EXACTLY (r14's wave-split reverted). Single change: att read directly
// from pre-transposed GLOBAL attG (coalesced in p, L1-hot 10KB) -- no LDS staging,
// ZERO barriers in this kernel.
__global__ __launch_bounds__(256) void k_gcn(const int* __restrict__ ctok,
                                             const int* __restrict__ cadj,
                                             const int* __restrict__ rtok,
                                             const int* __restrict__ radj,
                                             const float* __restrict__ hvp,
                                             const float* __restrict__ convb,
                                             const float* __restrict__ attG,  // [50][52]
                                             float* __restrict__ P) {
    __shared__ float hcv[4][SS][12];
    __shared__ float hcx[4][SS][12];
    __shared__ float aggL[4][SS][11];
    __shared__ int dgS[4][64];
    const int tid = threadIdx.x, wv = tid >> 6, lane = tid & 63;
    const int G = blockIdx.x * 4 + wv;

    const int* tb;
    const int* ab;
    if (G < NG) { tb = ctok + (long)G * SS; ab = cadj + (long)G * 2 * EE; }
    else        { int b = G - NG; tb = rtok + (long)b * SS; ab = radj + (long)b * 2 * EE; }

    const int e1s = ab[lane], e2s = ab[lane + 64];
    const int e1d = ab[EE + lane], e2d = ab[EE + lane + 64];
    const int myTok = (lane < SS) ? tb[lane] : 0;

    dgS[wv][lane] = 0;
    atomicAdd(&dgS[wv][e1d], 1);
    atomicAdd(&dgS[wv][e2d], 1);

    // gather -> hcv/hcx (convergent clamped shfl, r7 lesson)
    const float4* hv4 = (const float4*)hvp;
#pragma unroll
    for (int it = 0; it < 4; ++it) {
        const int idx = it * 64 + lane;
        int row = idx / 5;
        const int q = idx - row * 5;
        const int rowc = (row < SS) ? row : (SS - 1);
        const int t = __shfl(myTok, rowc);            // all 64 lanes execute
        if (idx < SS * 5) {
            const float4 a = hv4[(long)t * 5 + q];
            const float4 b = hv4[(long)(VOCAB * 5) + (long)t * 5 + q];
            const float4 w = make_float4(a.x + b.x, a.y + b.y, a.z + b.z, a.w + b.w);
            if (q == 0)      *(float4*)&hcv[wv][row][0] = w;
            else if (q == 1) *(float4*)&hcv[wv][row][4] = w;
            else if (q == 2) { hcv[wv][row][8] = w.x; hcv[wv][row][9] = w.y;
                               hcx[wv][row][0] = w.z; hcx[wv][row][1] = w.w; }
            else if (q == 3) { *(float2*)&hcx[wv][row][2] = make_float2(w.x, w.y);
                               *(float2*)&hcx[wv][row][4] = make_float2(w.z, w.w); }
            else             { *(float2*)&hcx[wv][row][6] = make_float2(w.x, w.y);
                               *(float2*)&hcx[wv][row][8] = make_float2(w.z, w.w); }
        }
    }

    float dv = 0.f;
    if (lane < SS) dv = rsqrtf((float)(dgS[wv][lane] + 1));

    float* aggW = &aggL[wv][0][0];
    for (int i = lane; i < SS * 11; i += 64) aggW[i] = 0.f;
    const float n1 = __shfl(dv, e1s) * __shfl(dv, e1d);
    const float n2 = __shfl(dv, e2s) * __shfl(dv, e2d);
#pragma unroll
    for (int c = 0; c < CC; c++) atomicAdd(&aggW[e1d * 11 + c], hcv[wv][e1s][c] * n1);
#pragma unroll
    for (int c = 0; c < CC; c++) atomicAdd(&aggW[e2d * 11 + c], hcv[wv][e2s][c] * n2);

    const int pc = (lane < SS) ? lane : (SS - 1);
    float xo[CC];
#pragma unroll
    for (int c = 0; c < CC; c++) xo[c] = hcx[wv][pc][c];

    const int p = lane;
    if (p < SS) {
        float gcn[CC];
        const float dp2 = dv * dv;
        const float4 s0 = *(const float4*)&hcv[wv][p][0];
        const float4 s1 = *(const float4*)&hcv[wv][p][4];
        const float s8 = hcv[wv][p][8], s9 = hcv[wv][p][9];
        gcn[0] = aggW[p * 11 + 0] + s0.x * dp2 + convb[0];
        gcn[1] = aggW[p * 11 + 1] + s0.y * dp2 + convb[1];
        gcn[2] = aggW[p * 11 + 2] + s0.z * dp2 + convb[2];
        gcn[3] = aggW[p * 11 + 3] + s0.w * dp2 + convb[3];
        gcn[4] = aggW[p * 11 + 4] + s1.x * dp2 + convb[4];
        gcn[5] = aggW[p * 11 + 5] + s1.y * dp2 + convb[5];
        gcn[6] = aggW[p * 11 + 6] + s1.z * dp2 + convb[6];
        gcn[7] = aggW[p * 11 + 7] + s1.w * dp2 + convb[7];
        gcn[8] = aggW[p * 11 + 8] + s8 * dp2 + convb[8];
        gcn[9] = aggW[p * 11 + 9] + s9 * dp2 + convb[9];

        float ax[CC];
#pragma unroll
        for (int c = 0; c < CC; c++) ax[c] = 0.f;
#pragma unroll 5
        for (int s = 0; s < SS; ++s) {
            const float a = attG[s * 52 + p];         // coalesced in p; L1-hot (10 KB)
#pragma unroll
            for (int c = 0; c < CC; c++) {
                const float xs = __uint_as_float(
                    __builtin_amdgcn_readlane(__float_as_uint(xo[c]), s));
                ax[c] = fmaf(a, xs, ax[c]);
            }
        }
        float4* o4 = (float4*)(P + (long)G * 1000 + p * 20);
        o4[0] = make_float4(gcn[0], gcn[1], gcn[2], gcn[3]);
        o4[1] = make_float4(gcn[4], gcn[5], gcn[6], gcn[7]);
        o4[2] = make_float4(gcn[8], gcn[9], ax[0], ax[1]);
        o4[3] = make_float4(ax[2], ax[3], ax[4], ax[5]);
        o4[4] = make_float4(ax[6], ax[7], ax[8], ax[9]);
    }
}

// ---------------- kernel 3: mpm x10 + final FFN fused, one block per batch b ----------------
// 512 blocks x 640 thr (10 waves): wave wv -> (t = wv>>1, which = wv&1), r12's verified
// register-mpm body, h2 -> LDS guS/grS; barrier; r7's verified P6 final + sigmoid.
__global__ __launch_bounds__(640) void k_mpmf(const float* __restrict__ P,
                                              const float* __restrict__ assign,
                                              const float* __restrict__ W1, const float* __restrict__ b1,
                                              const float* __restrict__ W2, const float* __restrict__ b2,
                                              const float* __restrict__ fW1, const float* __restrict__ fb1,
                                              const float* __restrict__ fW2, const float* __restrict__ fb2,
                                              float* __restrict__ out) {
    __shared__ float W2T[20][21];        // 1680 B
    __shared__ float asgL[SS][11];       // 2200 B
    __shared__ float h1L[10][SS][20];    // 40000 B
    __shared__ float guS[TT][20];        // 400 B
    __shared__ float grS[TT][20];        // 400 B
    __shared__ float fsum[256];          // 1024 B  -> 45704 B total
    const int tid = threadIdx.x, wv = tid >> 6, lane = tid & 63;
    const int b = blockIdx.x;
    const int t = wv >> 1, which = wv & 1;
    const int g = b * TT + t;

    for (int i = tid; i < 400; i += 640) W2T[i % 20][i / 20] = W2[i];  // W2T[j][k] = W2[k*20+j]
    for (int i = tid; i < SS * CC; i += 640) asgL[i / CC][i % CC] = assign[i];
    __syncthreads();   // B0: weights staged

    const float* Pc = P + (long)g * 1000;
    const float* Pr = P + (long)(NG + b) * 1000;
    const float* selfP = which ? Pr : Pc;
    const float* croP  = which ? Pc : Pr;

    const int p = lane;
    float self[CC], cro[CC];
    if (p < SS) {
        const float4* s4 = (const float4*)(selfP + p * 20);
        const float4 a0 = s4[0], a1 = s4[1], a2 = s4[2];
        self[0] = a0.x; self[1] = a0.y; self[2] = a0.z; self[3] = a0.w;
        self[4] = a1.x; self[5] = a1.y; self[6] = a1.z; self[7] = a1.w;
        self[8] = a2.x; self[9] = a2.y;
        const float4* c4 = (const float4*)(croP + p * 20);
        const float4 b0 = c4[2], b1q = c4[3], b2q = c4[4];
        cro[0] = b0.z; cro[1] = b0.w;
        cro[2] = b1q.x; cro[3] = b1q.y; cro[4] = b1q.z; cro[5] = b1q.w;
        cro[6] = b2q.x; cro[7] = b2q.y; cro[8] = b2q.z; cro[9] = b2q.w;
    }

    const int j = lane % 20;
    const int grp = lane / 20;
    float w2r[20];
#pragma unroll
    for (int k = 0; k < 20; k++) w2r[k] = W2T[j][k];

    // ---- phase A: per-node cos + h1 -> wave-private LDS slice ----
    if (p < SS) {
        float num = 0.f, na = 0.f, nc2 = 0.f;
#pragma unroll
        for (int c = 0; c < CC; c++) {
            float av = asgL[p][c];
            float a = av * self[c];
            float cx = av * cro[c];
            num = fmaf(a, cx, num);
            na = fmaf(a, a, na);
            nc2 = fmaf(cx, cx, nc2);
        }
        float cosv = num / fmaxf(sqrtf(na) * sqrtf(nc2), 1e-8f);
        float h1[20];
#pragma unroll
        for (int q = 0; q < 20; q++) h1[q] = fmaf(cosv, W1[q], b1[q]);
#pragma unroll
        for (int k = 0; k < CC; k++) {
            float sv = self[k];
#pragma unroll
            for (int q = 0; q < 20; q++) h1[q] = fmaf(sv, W1[(k + 1) * 20 + q], h1[q]);
        }
        float4* hw = (float4*)&h1L[wv][p][0];
        hw[0] = make_float4(fmaxf(h1[0], 0.f), fmaxf(h1[1], 0.f), fmaxf(h1[2], 0.f), fmaxf(h1[3], 0.f));
        hw[1] = make_float4(fmaxf(h1[4], 0.f), fmaxf(h1[5], 0.f), fmaxf(h1[6], 0.f), fmaxf(h1[7], 0.f));
        hw[2] = make_float4(fmaxf(h1[8], 0.f), fmaxf(h1[9], 0.f), fmaxf(h1[10], 0.f), fmaxf(h1[11], 0.f));
        hw[3] = make_float4(fmaxf(h1[12], 0.f), fmaxf(h1[13], 0.f), fmaxf(h1[14], 0.f), fmaxf(h1[15], 0.f));
        hw[4] = make_float4(fmaxf(h1[16], 0.f), fmaxf(h1[17], 0.f), fmaxf(h1[18], 0.f), fmaxf(h1[19], 0.f));
    }
    // same-wave ds_write -> ds_read: in-order DS pipe, no barrier

    // ---- phase B: h2[j] = max_s sum_k h1[s][k]*W2T[j][k] ----
    float part = -1e30f;
    if (grp < 3) {
        const int s0 = grp * 17;
        const int s1 = (grp == 2) ? SS : (s0 + 17);
        for (int s = s0; s < s1; ++s) {
            const float* hr = &h1L[wv][s][0];
            float tt = 0.f;
#pragma unroll
            for (int k = 0; k < 20; k++) tt = fmaf(hr[k], w2r[k], tt);
            part = fmaxf(part, tt);
        }
    }
    const float a0 = __shfl(part, j);           // convergent full-wave shfls
    const float a1 = __shfl(part, j + 20);
    const float a2 = __shfl(part, j + 40);
    if (lane < 20) {
        float h2 = fmaxf(fmaxf(a0, a1), a2) + b2[lane];
        (which ? grS[t] : guS[t])[lane] = h2;
    }
    __syncthreads();   // B1: guS/grS ready

    // ---- final FFN + reduce + sigmoid (r7's verified P6) ----
    float term = 0.f;
    if (tid < 200) {
        const int tt = tid / 40, jj = tid - tt * 40;
        float hvv = fb1[jj];
#pragma unroll
        for (int k = 0; k < 20; k++) {
            float u = guS[tt][k], r = grS[tt][k];
            hvv = fmaf(u, fW1[k * 40 + jj], hvv);
            hvv = fmaf(r, fW1[(20 + k) * 40 + jj], hvv);
            hvv = fmaf(u * r, fW1[(40 + k) * 40 + jj], hvv);
            hvv = fmaf(fabsf(u - r), fW1[(60 + k) * 40 + jj], hvv);
        }
        term = fmaxf(hvv, 0.f) * fW2[jj];
    }
    if (tid < 256) fsum[tid] = term;
    __syncthreads();   // B2
    if (wv == 0) {
        float s = fsum[lane] + fsum[lane + 64] + fsum[lane + 128] + fsum[lane + 192];
#pragma unroll
        for (int o = 32; o; o >>= 1) s += __shfl_xor(s, o);
        if (lane == 0) out[b] = 1.f / (1.f + expf(-(s + (float)TT * fb2[0])));
    }
}

extern "C" void kernel_launch(void* const* d_in, const int* in_sizes, int n_in,
                              void* d_out, int out_size, void* d_ws, size_t ws_size,
                              hipStream_t stream) {
    (void)in_sizes; (void)n_in; (void)out_size; (void)ws_size;
    const int* ctx_tok = (const int*)d_in[0];
    const int* resp_tok = (const int*)d_in[1];
    const int* ctx_adj = (const int*)d_in[2];
    const int* resp_adj = (const int*)d_in[3];
    const float* emb = (const float*)d_in[4];
    const float* convW = (const float*)d_in[5];
    const float* convb = (const float*)d_in[6];
    const float* crossW = (const float*)d_in[7];
    const float* att = (const float*)d_in[8];
    const float* assign = (const float*)d_in[9];
    const float* mpW1 = (const float*)d_in[10];
    const float* mpb1 = (const float*)d_in[11];
    const float* mpW2 = (const float*)d_in[12];
    const float* mpb2 = (const float*)d_in[13];
    const float* fW1 = (const float*)d_in[14];
    const float* fb1 = (const float*)d_in[15];
    const float* fW2 = (const float*)d_in[16];
    const float* fb2 = (const float*)d_in[17];

    float* ws = (float*)d_ws;
    float* hvp = ws;                       // [2][VOCAB][20]   = 845,120 floats
    float* P = hvp + 2 * V20;              // [3072][50][20]   = 3,072,000
    float* attG = P + (long)NALL * 1000;   // [50][52]         = 2,600
    float* outf = (float*)d_out;

    hipLaunchKernelGGL(k_prep, dim3(40), dim3(64), 0, stream, att, attG);
    hipLaunchKernelGGL(k_vocab, dim3((VOCAB + 63) / 64, 2), dim3(512), 0, stream,
                       emb, convW, crossW, hvp);
    hipLaunchKernelGGL(k_gcn, dim3(NALL / 4), dim3(256), 0, stream,
                       ctx_tok, ctx_adj, resp_tok, resp_adj, hvp, convb, attG, P);
    hipLaunchKernelGGL(k_mpmf, dim3(BB), dim3(640), 0, stream,
                       P, assign, mpW1, mpb1, mpW2, mpb2, fW1, fb1, fW2, fb2, outf);
}